// Round 11
// baseline (608.570 us; speedup 1.0000x reference)
//
#include <hip/hip_runtime.h>
#include <hip/hip_bf16.h>

#define N_NODES   10000
#define N_EDGES   320000
#define DIM       256
#define EDGE_DIM  64
#define FF_HIDDEN 512
#define GAMMA     0.5f
#define LSTR      260   // LDS row stride in shorts (520B): 2-way banks on tid-indexed reads

typedef __attribute__((ext_vector_type(8))) short bf16x8;
typedef __attribute__((ext_vector_type(4))) float f32x4;

static __device__ __forceinline__ unsigned short f2b(float f)
{
    union { __hip_bfloat16 b; unsigned short u; } c;
    c.b = __float2bfloat16(f);
    return c.u;
}
static __device__ __forceinline__ float b2f(unsigned short u)
{
    union { unsigned u32; float f; } c;
    c.u32 = ((unsigned)u) << 16;
    return c.f;
}

static __device__ __forceinline__ bf16x8 load_a_frag(const float* __restrict__ p)
{
    const float4 f0 = *(const float4*)p;
    const float4 f1 = *(const float4*)(p + 4);
    bf16x8 r;
    r[0] = (short)f2b(f0.x); r[1] = (short)f2b(f0.y);
    r[2] = (short)f2b(f0.z); r[3] = (short)f2b(f0.w);
    r[4] = (short)f2b(f1.x); r[5] = (short)f2b(f1.y);
    r[6] = (short)f2b(f1.z); r[7] = (short)f2b(f1.w);
    return r;
}

// ---------------------------------------------------------------------------
__global__ __launch_bounds__(256) void detect_kernel(const unsigned* __restrict__ ei,
                                                     int* __restrict__ flag)
{
    __shared__ int bad;
    if (threadIdx.x == 0) bad = 0;
    __syncthreads();
    int b = 0;
    for (int i = threadIdx.x; i < 1024; i += 256)
        if (ei[2 * i + 1] != 0u) b = 1;
    if (b) atomicAdd(&bad, 1);
    __syncthreads();
    if (threadIdx.x == 0) *flag = (bad == 0) ? 1 : 0;
}

__global__ __launch_bounds__(256) void convert_kernel(const unsigned* __restrict__ ei,
                                                      const int* __restrict__ flag,
                                                      int* __restrict__ src, int* __restrict__ dst,
                                                      int* __restrict__ counts)
{
    const int i = blockIdx.x * 256 + threadIdx.x;
    if (i >= N_EDGES) return;
    const int f = *flag;
    int s, d;
    if (f) { s = (int)ei[2 * i]; d = (int)ei[2 * (N_EDGES + i)]; }
    else   { s = (int)ei[i];     d = (int)ei[N_EDGES + i]; }
    src[i] = s;
    dst[i] = d;
    atomicAdd(&counts[d], 1);
}

__global__ __launch_bounds__(256) void scan_kernel(const int* __restrict__ counts,
                                                   int* __restrict__ row_start)
{
    __shared__ int lds[256];
    const int t = threadIdx.x;
    int vals[40];
    int tot = 0;
    const int base = t * 40;
#pragma unroll
    for (int j = 0; j < 40; ++j) {
        const int idx = base + j;
        const int c = (idx < N_NODES) ? counts[idx] : 0;
        vals[j] = tot;
        tot += c;
    }
    lds[t] = tot;
    __syncthreads();
    for (int off = 1; off < 256; off <<= 1) {
        const int tmp = (t >= off) ? lds[t - off] : 0;
        __syncthreads();
        lds[t] += tmp;
        __syncthreads();
    }
    const int ebase = lds[t] - tot;
#pragma unroll
    for (int j = 0; j < 40; ++j) {
        const int idx = base + j;
        if (idx < N_NODES) row_start[idx] = ebase + vals[j];
    }
    if (t == 0) row_start[N_NODES] = N_EDGES;
}

__global__ __launch_bounds__(256) void fill_kernel(const int* __restrict__ src,
                                                   const int* __restrict__ dst,
                                                   const int* __restrict__ row_start,
                                                   int* __restrict__ fillc,
                                                   int* __restrict__ csr_eid,
                                                   int* __restrict__ csr_src,
                                                   int* __restrict__ csr_dst)
{
    const int i = blockIdx.x * 256 + threadIdx.x;
    if (i >= N_EDGES) return;
    const int d = dst[i];
    const int pos = atomicAdd(&fillc[d], 1);
    const int slot = row_start[d] + pos;
    csr_eid[slot] = i;
    csr_src[slot] = src[i];
    csr_dst[slot] = d;
}

// ---------------------------------------------------------------------------
__global__ __launch_bounds__(256) void wconv_kernel(const float* __restrict__ W,
                                                    unsigned short* __restrict__ wT,
                                                    int K, int N)
{
    const int i = blockIdx.x * 256 + threadIdx.x;
    if (i >= K * N) return;
    const int k = i / N, n = i - k * N;
    wT[(size_t)n * K + k] = f2b(W[i]);
}

// edge_attr (f32, edge order) -> ea_bf (bf16, CSR slot order).
__global__ __launch_bounds__(256) void ea_conv(const float* __restrict__ ea,
                                               const int* __restrict__ csr_eid,
                                               unsigned short* __restrict__ out)
{
    const int slot = blockIdx.x * 16 + (threadIdx.x >> 4);
    const int l = threadIdx.x & 15;
    const int eid = csr_eid[slot];
    const float4 f = *(const float4*)(ea + (size_t)eid * EDGE_DIM + l * 4);
    ushort4 u;
    u.x = f2b(f.x); u.y = f2b(f.y); u.z = f2b(f.z); u.w = f2b(f.w);
    *(ushort4*)(out + (size_t)slot * EDGE_DIM + l * 4) = u;
}

// ---------------------------------------------------------------------------
// Wave-level register GEMM (no LDS), 4 waves/block, wave = 64x64 tile.
template <bool ABF16, int MODE>
__global__ __launch_bounds__(256) void wgemm(const void* __restrict__ Av,
                                             const unsigned short* __restrict__ wT,
                                             void* __restrict__ outv,
                                             int M, int K, int N,
                                             const unsigned short* __restrict__ epi_a,
                                             const float* __restrict__ epi_x)
{
    const int tid  = threadIdx.x;
    const int wave = tid >> 6;
    const int lane = tid & 63;
    const int l15  = lane & 15;
    const int l4   = lane >> 4;
    const int m0   = blockIdx.x * 64;
    const int n0   = blockIdx.y * 256 + wave * 64;

    f32x4 acc[4][4];
#pragma unroll
    for (int i = 0; i < 4; ++i)
#pragma unroll
        for (int j = 0; j < 4; ++j) acc[i][j] = f32x4{0.f, 0.f, 0.f, 0.f};

    int rowm[4];
#pragma unroll
    for (int i = 0; i < 4; ++i) rowm[i] = min(m0 + i * 16 + l15, M - 1);

    const int nk = K >> 6;
    for (int kt = 0; kt < nk; ++kt) {
        const int kb = kt * 64 + l4 * 8;
        bf16x8 bfr[2][4], afr[2][4];
#pragma unroll
        for (int ks = 0; ks < 2; ++ks)
#pragma unroll
            for (int j = 0; j < 4; ++j)
                bfr[ks][j] = *(const bf16x8*)(wT + (size_t)(n0 + j * 16 + l15) * K + kb + ks * 32);
#pragma unroll
        for (int ks = 0; ks < 2; ++ks)
#pragma unroll
            for (int i = 0; i < 4; ++i) {
                if (ABF16)
                    afr[ks][i] = *(const bf16x8*)((const unsigned short*)Av + (size_t)rowm[i] * K + kb + ks * 32);
                else
                    afr[ks][i] = load_a_frag((const float*)Av + (size_t)rowm[i] * K + kb + ks * 32);
            }
#pragma unroll
        for (int ks = 0; ks < 2; ++ks)
#pragma unroll
            for (int i = 0; i < 4; ++i)
#pragma unroll
                for (int j = 0; j < 4; ++j)
                    acc[i][j] = __builtin_amdgcn_mfma_f32_16x16x32_bf16(bfr[ks][j], afr[ks][i], acc[i][j], 0, 0, 0);
    }

#pragma unroll
    for (int i = 0; i < 4; ++i) {
        const int m = m0 + i * 16 + l15;
        if (m < M) {
#pragma unroll
            for (int j = 0; j < 4; ++j) {
                const size_t oi = (size_t)m * N + n0 + j * 16 + l4 * 4;
                if (MODE == 2) {
                    const ushort4 ea = *(const ushort4*)(epi_a + oi);
                    const float4  ex = *(const float4*)(epi_x + oi);
                    float4 v;
                    v.x = fmaxf(acc[i][j][0] + b2f(ea.x), 0.f) + ex.x;
                    v.y = fmaxf(acc[i][j][1] + b2f(ea.y), 0.f) + ex.y;
                    v.z = fmaxf(acc[i][j][2] + b2f(ea.z), 0.f) + ex.z;
                    v.w = fmaxf(acc[i][j][3] + b2f(ea.w), 0.f) + ex.w;
                    *(float4*)((float*)outv + oi) = v;
                } else {
                    float a0 = acc[i][j][0], a1 = acc[i][j][1];
                    float a2 = acc[i][j][2], a3 = acc[i][j][3];
                    if (MODE == 1) {
                        a0 = fmaxf(a0, 0.f); a1 = fmaxf(a1, 0.f);
                        a2 = fmaxf(a2, 0.f); a3 = fmaxf(a3, 0.f);
                    }
                    ushort4 u;
                    u.x = f2b(a0); u.y = f2b(a1); u.z = f2b(a2); u.w = f2b(a3);
                    *(ushort4*)((unsigned short*)outv + oi) = u;
                }
            }
        }
    }
}

// ---------------------------------------------------------------------------
// Fused hop v3. Block = 64 CSR slots, 4 waves.
// Phase 1 (r9/r10-verified): MFMA-recompute e-tile -> LDS val (pure e).
// Phase 2 (r9 exchange + r8 gather): ONE serial pass over the 64 slots,
// thread t owns dim t. Per slot all 256 threads read one FULL 512B row of
// h_prev1 (coalesced) + val from LDS (2-way banks), relu-add, accumulate;
// on segment change flush with a single dword atomicAdd per thread
// (~3 flushes/block -> ~15MB total atomic write traffic, r9-measured).
__global__ __launch_bounds__(256) void fused_hop(const unsigned short* __restrict__ h_prev1,
                                                 const unsigned short* __restrict__ ea,
                                                 const unsigned short* __restrict__ weT,
                                                 const int* __restrict__ csr_src,
                                                 const int* __restrict__ csr_dst,
                                                 float* __restrict__ agg)
{
    __shared__ unsigned short val[64 * LSTR];
    __shared__ int dst_l[64];
    __shared__ int src_l[64];

    const int tid  = threadIdx.x;
    const int wave = tid >> 6;
    const int lane = tid & 63;
    const int l15  = lane & 15;
    const int l4   = lane >> 4;
    const int wc0  = wave * 64;
    const int s0   = blockIdx.x * 64;

    if (tid < 64) {
        dst_l[tid] = csr_dst[s0 + tid];
        src_l[tid] = csr_src[s0 + tid];
    }

    // ---- Phase 1: e = ea @ W_e for 64 slots (wave computes cols wc0..wc0+63)
    bf16x8 bfr[2][4];
#pragma unroll
    for (int ks = 0; ks < 2; ++ks)
#pragma unroll
        for (int j = 0; j < 4; ++j)
            bfr[ks][j] = *(const bf16x8*)(weT + (size_t)(wc0 + j * 16 + l15) * 64 + ks * 32 + l4 * 8);

    bf16x8 afr[2][4];
#pragma unroll
    for (int ks = 0; ks < 2; ++ks)
#pragma unroll
        for (int i = 0; i < 4; ++i)
            afr[ks][i] = *(const bf16x8*)(ea + (size_t)(s0 + i * 16 + l15) * 64 + ks * 32 + l4 * 8);

    f32x4 acc[4][4];
#pragma unroll
    for (int i = 0; i < 4; ++i)
#pragma unroll
        for (int j = 0; j < 4; ++j) acc[i][j] = f32x4{0.f, 0.f, 0.f, 0.f};
#pragma unroll
    for (int ks = 0; ks < 2; ++ks)
#pragma unroll
        for (int i = 0; i < 4; ++i)
#pragma unroll
            for (int j = 0; j < 4; ++j)
                acc[i][j] = __builtin_amdgcn_mfma_f32_16x16x32_bf16(bfr[ks][j], afr[ks][i], acc[i][j], 0, 0, 0);

#pragma unroll
    for (int i = 0; i < 4; ++i)
#pragma unroll
        for (int j = 0; j < 4; ++j) {
            ushort4 u;
            u.x = f2b(acc[i][j][0]); u.y = f2b(acc[i][j][1]);
            u.z = f2b(acc[i][j][2]); u.w = f2b(acc[i][j][3]);
            *(ushort4*)(&val[(i * 16 + l15) * LSTR + wc0 + j * 16 + l4 * 4]) = u;
        }
    __syncthreads();

    // ---- Phase 2: serial segmented sum; thread t owns dim t.
    float sum = 0.f;
    int cur = dst_l[0];
#pragma unroll 8
    for (int s = 0; s < 64; ++s) {
        const int nd = dst_l[s];
        if (nd != cur) {
            atomicAdd(&agg[(size_t)cur * DIM + tid], sum);
            sum = 0.f;
            cur = nd;
        }
        const float h = b2f(h_prev1[(size_t)src_l[s] * DIM + tid]);   // full-row 512B
        sum += fmaxf(h + b2f(val[s * LSTR + tid]), 0.f);
    }
    atomicAdd(&agg[(size_t)cur * DIM + tid], sum);
}

// h_out = bf16(agg - GAMMA*deg*h_prev2); h_prev2 may be null (hop 1).
__global__ __launch_bounds__(256) void fixup_kernel(const float* __restrict__ agg,
                                                    const unsigned short* __restrict__ h_prev2,
                                                    const int* __restrict__ row_start,
                                                    unsigned short* __restrict__ h_out)
{
    const int idx = blockIdx.x * 256 + threadIdx.x;
    const int n  = idx >> 6;
    const int d4 = (idx & 63) * 4;
    const float4 a = *(const float4*)(agg + (size_t)n * DIM + d4);
    float4 r = a;
    if (h_prev2) {
        const float gd = GAMMA * (float)(row_start[n + 1] - row_start[n]);
        const ushort4 p2 = *(const ushort4*)(h_prev2 + (size_t)n * DIM + d4);
        r.x -= gd * b2f(p2.x); r.y -= gd * b2f(p2.y);
        r.z -= gd * b2f(p2.z); r.w -= gd * b2f(p2.w);
    }
    ushort4 o;
    o.x = f2b(r.x); o.y = f2b(r.y); o.z = f2b(r.z); o.w = f2b(r.w);
    *(ushort4*)(h_out + (size_t)n * DIM + d4) = o;
}

// ---------------------------------------------------------------------------
__global__ __launch_bounds__(256) void attn_kernel(const unsigned short* __restrict__ h0,
                                                   const unsigned short* __restrict__ h1,
                                                   const unsigned short* __restrict__ h2,
                                                   const unsigned short* __restrict__ h3,
                                                   const float* __restrict__ att_a,
                                                   unsigned short* __restrict__ out)
{
    const int n = blockIdx.x;
    const int t = threadIdx.x;
    const size_t i = (size_t)n * DIM + t;
    const float q = b2f(h0[i]);
    float hk[4];
    hk[0] = q; hk[1] = b2f(h1[i]); hk[2] = b2f(h2[i]); hk[3] = b2f(h3[i]);
    const float a = att_a[t];
    float sc[4];
#pragma unroll
    for (int k = 0; k < 4; ++k) {
        float v = tanhf(hk[k] + q) * a;
#pragma unroll
        for (int off = 32; off > 0; off >>= 1)
            v += __shfl_xor(v, off, 64);
        sc[k] = v;
    }
    const float mx = fmaxf(fmaxf(sc[0], sc[1]), fmaxf(sc[2], sc[3]));
    float ex[4], se = 0.f;
#pragma unroll
    for (int k = 0; k < 4; ++k) { ex[k] = __expf(sc[k] - mx); se += ex[k]; }
    const float inv = 1.f / se;
    float o = 0.f;
#pragma unroll
    for (int k = 0; k < 4; ++k) o += ex[k] * inv * hk[k];
    out[i] = f2b(o);
}

// ---------------------------------------------------------------------------
extern "C" void kernel_launch(void* const* d_in, const int* in_sizes, int n_in,
                              void* d_out, int out_size, void* d_ws, size_t ws_size,
                              hipStream_t stream)
{
    const float*    x         = (const float*)d_in[0];
    const unsigned* ei        = (const unsigned*)d_in[1];
    const float*    edge_attr = (const float*)d_in[2];
    const float*    W_x       = (const float*)d_in[3];
    const float*    W_e       = (const float*)d_in[4];
    const float*    att_a     = (const float*)d_in[5];
    const float*    W_ff1     = (const float*)d_in[6];
    const float*    W_ff2     = (const float*)d_in[7];

    char* ws = (char*)d_ws;
    size_t off = 0;
    auto alloc = [&](size_t bytes) -> void* {
        void* p = ws + off;
        off = (off + bytes + 255) & ~(size_t)255;
        return p;
    };
    int*   flag      = (int*)alloc(4);
    int*   src32     = (int*)alloc((size_t)N_EDGES * 4);
    int*   dst32     = (int*)alloc((size_t)N_EDGES * 4);
    int*   counts    = (int*)alloc((size_t)2 * N_NODES * 4);
    int*   fillc     = counts + N_NODES;
    int*   row_start = (int*)alloc((size_t)(N_NODES + 1) * 4);
    int*   csr_eid   = (int*)alloc((size_t)N_EDGES * 4);
    int*   csr_src   = (int*)alloc((size_t)N_EDGES * 4);
    int*   csr_dst   = (int*)alloc((size_t)N_EDGES * 4);
    unsigned short* ea_bf = (unsigned short*)alloc((size_t)N_EDGES * EDGE_DIM * 2);
    float* agg       = (float*)alloc((size_t)N_NODES * DIM * 4);
    unsigned short* h0b   = (unsigned short*)alloc((size_t)N_NODES * DIM * 2);
    unsigned short* h1b   = (unsigned short*)alloc((size_t)N_NODES * DIM * 2);
    unsigned short* h2b   = (unsigned short*)alloc((size_t)N_NODES * DIM * 2);
    unsigned short* h3b   = (unsigned short*)alloc((size_t)N_NODES * DIM * 2);
    unsigned short* attnb = (unsigned short*)alloc((size_t)N_NODES * DIM * 2);
    unsigned short* hidb  = (unsigned short*)alloc((size_t)N_NODES * FF_HIDDEN * 2);
    unsigned short* wxT   = (unsigned short*)alloc((size_t)DIM * DIM * 2);
    unsigned short* weT   = (unsigned short*)alloc((size_t)DIM * EDGE_DIM * 2);
    unsigned short* wff1T = (unsigned short*)alloc((size_t)FF_HIDDEN * DIM * 2);
    unsigned short* wff2T = (unsigned short*)alloc((size_t)DIM * FF_HIDDEN * 2);
    if (off > ws_size) return;

    const int egrid = (N_EDGES + 255) / 256;

    hipMemsetAsync(counts, 0, (size_t)2 * N_NODES * 4, stream);
    detect_kernel<<<1, 256, 0, stream>>>(ei, flag);
    convert_kernel<<<egrid, 256, 0, stream>>>(ei, flag, src32, dst32, counts);
    scan_kernel<<<1, 256, 0, stream>>>(counts, row_start);
    fill_kernel<<<egrid, 256, 0, stream>>>(src32, dst32, row_start, fillc,
                                           csr_eid, csr_src, csr_dst);

    wconv_kernel<<<(DIM * DIM + 255) / 256, 256, 0, stream>>>(W_x, wxT, DIM, DIM);
    wconv_kernel<<<(EDGE_DIM * DIM + 255) / 256, 256, 0, stream>>>(W_e, weT, EDGE_DIM, DIM);
    wconv_kernel<<<(DIM * FF_HIDDEN + 255) / 256, 256, 0, stream>>>(W_ff1, wff1T, DIM, FF_HIDDEN);
    wconv_kernel<<<(FF_HIDDEN * DIM + 255) / 256, 256, 0, stream>>>(W_ff2, wff2T, FF_HIDDEN, DIM);

    // CSR-ordered bf16 edge features (41 MB, read by each hop)
    ea_conv<<<N_EDGES / 16, 256, 0, stream>>>(edge_attr, csr_eid, ea_bf);

    // h0 = x @ W_x -> bf16
    wgemm<false, 0><<<dim3(157, 1), 256, 0, stream>>>(x, wxT, h0b,
        N_NODES, DIM, DIM, nullptr, nullptr);

    const size_t aggbytes = (size_t)N_NODES * DIM * 4;
    // hop 1
    hipMemsetAsync(agg, 0, aggbytes, stream);
    fused_hop<<<N_EDGES / 64, 256, 0, stream>>>(h0b, ea_bf, weT, csr_src, csr_dst, agg);
    fixup_kernel<<<N_NODES * 64 / 256, 256, 0, stream>>>(agg, nullptr, row_start, h1b);
    // hop 2
    hipMemsetAsync(agg, 0, aggbytes, stream);
    fused_hop<<<N_EDGES / 64, 256, 0, stream>>>(h1b, ea_bf, weT, csr_src, csr_dst, agg);
    fixup_kernel<<<N_NODES * 64 / 256, 256, 0, stream>>>(agg, h0b, row_start, h2b);
    // hop 3
    hipMemsetAsync(agg, 0, aggbytes, stream);
    fused_hop<<<N_EDGES / 64, 256, 0, stream>>>(h2b, ea_bf, weT, csr_src, csr_dst, agg);
    fixup_kernel<<<N_NODES * 64 / 256, 256, 0, stream>>>(agg, h1b, row_start, h3b);

    attn_kernel<<<N_NODES, 256, 0, stream>>>(h0b, h1b, h2b, h3b, att_a, attnb);

    // hidden = relu(attn @ W_ff1) -> bf16
    wgemm<true, 1><<<dim3(157, 2), 256, 0, stream>>>(attnb, wff1T, hidb,
        N_NODES, DIM, FF_HIDDEN, nullptr, nullptr);
    // d_out = x + relu(attn + hidden @ W_ff2)
    wgemm<true, 2><<<dim3(157, 1), 256, 0, stream>>>(hidb, wff2T, d_out,
        N_NODES, FF_HIDDEN, DIM, attnb, x);
}

// Round 12
// 345.940 us; speedup vs baseline: 1.7592x; 1.7592x over previous
//
#include <hip/hip_runtime.h>
#include <hip/hip_bf16.h>

#define N_NODES   10000
#define N_EDGES   320000
#define DIM       256
#define EDGE_DIM  64
#define FF_HIDDEN 512
#define GAMMA     0.5f

typedef __attribute__((ext_vector_type(8))) short bf16x8;
typedef __attribute__((ext_vector_type(4))) float f32x4;

static __device__ __forceinline__ unsigned short f2b(float f)
{
    union { __hip_bfloat16 b; unsigned short u; } c;
    c.b = __float2bfloat16(f);
    return c.u;
}
static __device__ __forceinline__ float b2f(unsigned short u)
{
    union { unsigned u32; float f; } c;
    c.u32 = ((unsigned)u) << 16;
    return c.f;
}

// f32 -> fp8 e4m3fn (round-half-up, denormals flushed, clamp to 448).
static __device__ __forceinline__ unsigned f2fp8(float f)
{
    union { float f; unsigned u; } c; c.f = f;
    const unsigned s = (c.u >> 24) & 0x80u;
    int v = (int)(((c.u & 0x7FFFFFFFu) + 0x00080000u) >> 20) - 960;
    v = (v < 8) ? 0 : ((v > 126) ? 126 : v);
    return s | (unsigned)v;
}
// fp8 e4m3fn -> f32 (denormals -> 0)
static __device__ __forceinline__ float fp8tof(unsigned u)
{
    unsigned v = ((u & 0x7Fu) << 4) + 0x3C00u;
    v = (u & 0x78u) ? v : 0u;
    v |= (u & 0x80u) << 8;
    union { unsigned u; float f; } c; c.u = v << 16;
    return c.f;
}

static __device__ __forceinline__ bf16x8 load_a_frag(const float* __restrict__ p)
{
    const float4 f0 = *(const float4*)p;
    const float4 f1 = *(const float4*)(p + 4);
    bf16x8 r;
    r[0] = (short)f2b(f0.x); r[1] = (short)f2b(f0.y);
    r[2] = (short)f2b(f0.z); r[3] = (short)f2b(f0.w);
    r[4] = (short)f2b(f1.x); r[5] = (short)f2b(f1.y);
    r[6] = (short)f2b(f1.z); r[7] = (short)f2b(f1.w);
    return r;
}

// ---------------------------------------------------------------------------
__global__ __launch_bounds__(256) void detect_kernel(const unsigned* __restrict__ ei,
                                                     int* __restrict__ flag)
{
    __shared__ int bad;
    if (threadIdx.x == 0) bad = 0;
    __syncthreads();
    int b = 0;
    for (int i = threadIdx.x; i < 1024; i += 256)
        if (ei[2 * i + 1] != 0u) b = 1;
    if (b) atomicAdd(&bad, 1);
    __syncthreads();
    if (threadIdx.x == 0) *flag = (bad == 0) ? 1 : 0;
}

__global__ __launch_bounds__(256) void convert_kernel(const unsigned* __restrict__ ei,
                                                      const int* __restrict__ flag,
                                                      int* __restrict__ src, int* __restrict__ dst,
                                                      int* __restrict__ counts)
{
    const int i = blockIdx.x * 256 + threadIdx.x;
    if (i >= N_EDGES) return;
    const int f = *flag;
    int s, d;
    if (f) { s = (int)ei[2 * i]; d = (int)ei[2 * (N_EDGES + i)]; }
    else   { s = (int)ei[i];     d = (int)ei[N_EDGES + i]; }
    src[i] = s;
    dst[i] = d;
    atomicAdd(&counts[d], 1);
}

__global__ __launch_bounds__(256) void scan_kernel(const int* __restrict__ counts,
                                                   int* __restrict__ row_start)
{
    __shared__ int lds[256];
    const int t = threadIdx.x;
    int vals[40];
    int tot = 0;
    const int base = t * 40;
#pragma unroll
    for (int j = 0; j < 40; ++j) {
        const int idx = base + j;
        const int c = (idx < N_NODES) ? counts[idx] : 0;
        vals[j] = tot;
        tot += c;
    }
    lds[t] = tot;
    __syncthreads();
    for (int off = 1; off < 256; off <<= 1) {
        const int tmp = (t >= off) ? lds[t - off] : 0;
        __syncthreads();
        lds[t] += tmp;
        __syncthreads();
    }
    const int ebase = lds[t] - tot;
#pragma unroll
    for (int j = 0; j < 40; ++j) {
        const int idx = base + j;
        if (idx < N_NODES) row_start[idx] = ebase + vals[j];
    }
    if (t == 0) row_start[N_NODES] = N_EDGES;
}

__global__ __launch_bounds__(256) void fill_kernel(const int* __restrict__ src,
                                                   const int* __restrict__ dst,
                                                   const int* __restrict__ row_start,
                                                   int* __restrict__ fillc,
                                                   int* __restrict__ csr_eid,
                                                   int* __restrict__ csr_src)
{
    const int i = blockIdx.x * 256 + threadIdx.x;
    if (i >= N_EDGES) return;
    const int d = dst[i];
    const int pos = atomicAdd(&fillc[d], 1);
    const int slot = row_start[d] + pos;
    csr_eid[slot] = i;
    csr_src[slot] = src[i];
}

// ---------------------------------------------------------------------------
__global__ __launch_bounds__(256) void wconv_kernel(const float* __restrict__ W,
                                                    unsigned short* __restrict__ wT,
                                                    int K, int N)
{
    const int i = blockIdx.x * 256 + threadIdx.x;
    if (i >= K * N) return;
    const int k = i / N, n = i - k * N;
    wT[(size_t)n * K + k] = f2b(W[i]);
}

// ---------------------------------------------------------------------------
// Wave-level register GEMM (no LDS), 4 waves/block, wave = 64x64 tile.
template <bool ABF16, int MODE>
__global__ __launch_bounds__(256) void wgemm(const void* __restrict__ Av,
                                             const unsigned short* __restrict__ wT,
                                             void* __restrict__ outv,
                                             int M, int K, int N,
                                             const unsigned short* __restrict__ epi_a,
                                             const float* __restrict__ epi_x)
{
    const int tid  = threadIdx.x;
    const int wave = tid >> 6;
    const int lane = tid & 63;
    const int l15  = lane & 15;
    const int l4   = lane >> 4;
    const int m0   = blockIdx.x * 64;
    const int n0   = blockIdx.y * 256 + wave * 64;

    f32x4 acc[4][4];
#pragma unroll
    for (int i = 0; i < 4; ++i)
#pragma unroll
        for (int j = 0; j < 4; ++j) acc[i][j] = f32x4{0.f, 0.f, 0.f, 0.f};

    int rowm[4];
#pragma unroll
    for (int i = 0; i < 4; ++i) rowm[i] = min(m0 + i * 16 + l15, M - 1);

    const int nk = K >> 6;
    for (int kt = 0; kt < nk; ++kt) {
        const int kb = kt * 64 + l4 * 8;
        bf16x8 bfr[2][4], afr[2][4];
#pragma unroll
        for (int ks = 0; ks < 2; ++ks)
#pragma unroll
            for (int j = 0; j < 4; ++j)
                bfr[ks][j] = *(const bf16x8*)(wT + (size_t)(n0 + j * 16 + l15) * K + kb + ks * 32);
#pragma unroll
        for (int ks = 0; ks < 2; ++ks)
#pragma unroll
            for (int i = 0; i < 4; ++i) {
                if (ABF16)
                    afr[ks][i] = *(const bf16x8*)((const unsigned short*)Av + (size_t)rowm[i] * K + kb + ks * 32);
                else
                    afr[ks][i] = load_a_frag((const float*)Av + (size_t)rowm[i] * K + kb + ks * 32);
            }
#pragma unroll
        for (int ks = 0; ks < 2; ++ks)
#pragma unroll
            for (int i = 0; i < 4; ++i)
#pragma unroll
                for (int j = 0; j < 4; ++j)
                    acc[i][j] = __builtin_amdgcn_mfma_f32_16x16x32_bf16(bfr[ks][j], afr[ks][i], acc[i][j], 0, 0, 0);
    }

#pragma unroll
    for (int i = 0; i < 4; ++i) {
        const int m = m0 + i * 16 + l15;
        if (m < M) {
#pragma unroll
            for (int j = 0; j < 4; ++j) {
                const size_t oi = (size_t)m * N + n0 + j * 16 + l4 * 4;
                if (MODE == 2) {
                    const ushort4 ea = *(const ushort4*)(epi_a + oi);
                    const float4  ex = *(const float4*)(epi_x + oi);
                    float4 v;
                    v.x = fmaxf(acc[i][j][0] + b2f(ea.x), 0.f) + ex.x;
                    v.y = fmaxf(acc[i][j][1] + b2f(ea.y), 0.f) + ex.y;
                    v.z = fmaxf(acc[i][j][2] + b2f(ea.z), 0.f) + ex.z;
                    v.w = fmaxf(acc[i][j][3] + b2f(ea.w), 0.f) + ex.w;
                    *(float4*)((float*)outv + oi) = v;
                } else {
                    float a0 = acc[i][j][0], a1 = acc[i][j][1];
                    float a2 = acc[i][j][2], a3 = acc[i][j][3];
                    if (MODE == 1) {
                        a0 = fmaxf(a0, 0.f); a1 = fmaxf(a1, 0.f);
                        a2 = fmaxf(a2, 0.f); a3 = fmaxf(a3, 0.f);
                    }
                    ushort4 u;
                    u.x = f2b(a0); u.y = f2b(a1); u.z = f2b(a2); u.w = f2b(a3);
                    *(ushort4*)((unsigned short*)outv + oi) = u;
                }
            }
        }
    }
}

// ---------------------------------------------------------------------------
// e-GEMM -> fp8: block owns CSR slots [s0, s0+64). A-rows gathered from
// edge_attr via csr_eid; compute in regs (no input LDS); fp8-encode through a
// 64x272B LDS tile; stores are 64B/thread, 4KB/wave contiguous, CSR order.
__global__ __launch_bounds__(256) void egemm_fp8(const float* __restrict__ A,
                                                 const unsigned short* __restrict__ wT,
                                                 unsigned char* __restrict__ e_out,
                                                 const int* __restrict__ csr_eid)
{
    __shared__ unsigned char et[64 * 272];   // 17408 B
    const int tid  = threadIdx.x;
    const int wave = tid >> 6;
    const int lane = tid & 63;
    const int l15  = lane & 15;
    const int l4   = lane >> 4;
    const int wc0  = wave * 64;
    const int s0   = blockIdx.x * 64;

    bf16x8 bfr[2][4];
#pragma unroll
    for (int ks = 0; ks < 2; ++ks)
#pragma unroll
        for (int j = 0; j < 4; ++j)
            bfr[ks][j] = *(const bf16x8*)(wT + (size_t)(wc0 + j * 16 + l15) * 64 + ks * 32 + l4 * 8);

    int eid[4];
#pragma unroll
    for (int i = 0; i < 4; ++i) eid[i] = csr_eid[s0 + i * 16 + l15];

    bf16x8 afr[2][4];
#pragma unroll
    for (int ks = 0; ks < 2; ++ks)
#pragma unroll
        for (int i = 0; i < 4; ++i)
            afr[ks][i] = load_a_frag(A + (size_t)eid[i] * 64 + ks * 32 + l4 * 8);

    f32x4 acc[4][4];
#pragma unroll
    for (int i = 0; i < 4; ++i)
#pragma unroll
        for (int j = 0; j < 4; ++j) acc[i][j] = f32x4{0.f, 0.f, 0.f, 0.f};
#pragma unroll
    for (int ks = 0; ks < 2; ++ks)
#pragma unroll
        for (int i = 0; i < 4; ++i)
#pragma unroll
            for (int j = 0; j < 4; ++j)
                acc[i][j] = __builtin_amdgcn_mfma_f32_16x16x32_bf16(bfr[ks][j], afr[ks][i], acc[i][j], 0, 0, 0);

    // fp8-encode into LDS tile (4B per acc group)
#pragma unroll
    for (int i = 0; i < 4; ++i)
#pragma unroll
        for (int j = 0; j < 4; ++j) {
            const unsigned p = f2fp8(acc[i][j][0])
                             | (f2fp8(acc[i][j][1]) << 8)
                             | (f2fp8(acc[i][j][2]) << 16)
                             | (f2fp8(acc[i][j][3]) << 24);
            *(unsigned*)(&et[(i * 16 + l15) * 272 + wc0 + j * 16 + l4 * 4]) = p;
        }
    __syncthreads();

    // copy out: thread t -> row t>>2, 64B chunk t&3
    const unsigned char* sp = et + (tid >> 2) * 272 + (tid & 3) * 64;
    unsigned char* dp = e_out + (size_t)(s0 + (tid >> 2)) * 256 + (tid & 3) * 64;
#pragma unroll
    for (int v = 0; v < 4; ++v)
        *(uint4*)(dp + v * 16) = *(const uint4*)(sp + v * 16);
}

// ---------------------------------------------------------------------------
// Hop (r8 structure): wave-per-node, 4 dims/lane, 8-edge MLP unroll.
// e is fp8 in CSR order (pure sequential 256B rows); h bf16.
__global__ __launch_bounds__(256) void hop_kernel(const unsigned short* __restrict__ h_prev1,
                                                  const unsigned short* __restrict__ h_prev2,
                                                  const unsigned char* __restrict__ e,
                                                  const int* __restrict__ row_start,
                                                  const int* __restrict__ csr_src,
                                                  unsigned short* __restrict__ h_out)
{
    const int wave = threadIdx.x >> 6;
    const int lane = threadIdx.x & 63;
    const int n = blockIdx.x * 4 + wave;
    const int d4 = lane * 4;
    const int rb = row_start[n];
    const int re = row_start[n + 1];

    float4 acc = {0.f, 0.f, 0.f, 0.f};
    int s = rb;
    for (; s + 8 <= re; s += 8) {
        int idx[8];
        unsigned ev[8];
        ushort4 hv[8];
#pragma unroll
        for (int u = 0; u < 8; ++u) idx[u] = csr_src[s + u];
#pragma unroll
        for (int u = 0; u < 8; ++u) ev[u] = *(const unsigned*)(e + (size_t)(s + u) * 256 + d4);
#pragma unroll
        for (int u = 0; u < 8; ++u) hv[u] = *(const ushort4*)(h_prev1 + (size_t)idx[u] * DIM + d4);
#pragma unroll
        for (int u = 0; u < 8; ++u) {
            acc.x += fmaxf(b2f(hv[u].x) + fp8tof(ev[u] & 255u), 0.f);
            acc.y += fmaxf(b2f(hv[u].y) + fp8tof((ev[u] >> 8) & 255u), 0.f);
            acc.z += fmaxf(b2f(hv[u].z) + fp8tof((ev[u] >> 16) & 255u), 0.f);
            acc.w += fmaxf(b2f(hv[u].w) + fp8tof(ev[u] >> 24), 0.f);
        }
    }
    for (; s < re; ++s) {
        const int sr = csr_src[s];
        const unsigned ev = *(const unsigned*)(e + (size_t)s * 256 + d4);
        const ushort4 hv = *(const ushort4*)(h_prev1 + (size_t)sr * DIM + d4);
        acc.x += fmaxf(b2f(hv.x) + fp8tof(ev & 255u), 0.f);
        acc.y += fmaxf(b2f(hv.y) + fp8tof((ev >> 8) & 255u), 0.f);
        acc.z += fmaxf(b2f(hv.z) + fp8tof((ev >> 16) & 255u), 0.f);
        acc.w += fmaxf(b2f(hv.w) + fp8tof(ev >> 24), 0.f);
    }
    if (h_prev2) {
        const float gd = GAMMA * (float)(re - rb);
        const ushort4 p2 = *(const ushort4*)(h_prev2 + (size_t)n * DIM + d4);
        acc.x -= gd * b2f(p2.x); acc.y -= gd * b2f(p2.y);
        acc.z -= gd * b2f(p2.z); acc.w -= gd * b2f(p2.w);
    }
    ushort4 o;
    o.x = f2b(acc.x); o.y = f2b(acc.y); o.z = f2b(acc.z); o.w = f2b(acc.w);
    *(ushort4*)(h_out + (size_t)n * DIM + d4) = o;
}

// ---------------------------------------------------------------------------
__global__ __launch_bounds__(256) void attn_kernel(const unsigned short* __restrict__ h0,
                                                   const unsigned short* __restrict__ h1,
                                                   const unsigned short* __restrict__ h2,
                                                   const unsigned short* __restrict__ h3,
                                                   const float* __restrict__ att_a,
                                                   unsigned short* __restrict__ out)
{
    const int n = blockIdx.x;
    const int t = threadIdx.x;
    const size_t i = (size_t)n * DIM + t;
    const float q = b2f(h0[i]);
    float hk[4];
    hk[0] = q; hk[1] = b2f(h1[i]); hk[2] = b2f(h2[i]); hk[3] = b2f(h3[i]);
    const float a = att_a[t];
    float sc[4];
#pragma unroll
    for (int k = 0; k < 4; ++k) {
        float v = tanhf(hk[k] + q) * a;
#pragma unroll
        for (int off = 32; off > 0; off >>= 1)
            v += __shfl_xor(v, off, 64);
        sc[k] = v;
    }
    const float mx = fmaxf(fmaxf(sc[0], sc[1]), fmaxf(sc[2], sc[3]));
    float ex[4], se = 0.f;
#pragma unroll
    for (int k = 0; k < 4; ++k) { ex[k] = __expf(sc[k] - mx); se += ex[k]; }
    const float inv = 1.f / se;
    float o = 0.f;
#pragma unroll
    for (int k = 0; k < 4; ++k) o += ex[k] * inv * hk[k];
    out[i] = f2b(o);
}

// ---------------------------------------------------------------------------
extern "C" void kernel_launch(void* const* d_in, const int* in_sizes, int n_in,
                              void* d_out, int out_size, void* d_ws, size_t ws_size,
                              hipStream_t stream)
{
    const float*    x         = (const float*)d_in[0];
    const unsigned* ei        = (const unsigned*)d_in[1];
    const float*    edge_attr = (const float*)d_in[2];
    const float*    W_x       = (const float*)d_in[3];
    const float*    W_e       = (const float*)d_in[4];
    const float*    att_a     = (const float*)d_in[5];
    const float*    W_ff1     = (const float*)d_in[6];
    const float*    W_ff2     = (const float*)d_in[7];

    char* ws = (char*)d_ws;
    size_t off = 0;
    auto alloc = [&](size_t bytes) -> void* {
        void* p = ws + off;
        off = (off + bytes + 255) & ~(size_t)255;
        return p;
    };
    int*   flag      = (int*)alloc(4);
    int*   src32     = (int*)alloc((size_t)N_EDGES * 4);
    int*   dst32     = (int*)alloc((size_t)N_EDGES * 4);
    int*   counts    = (int*)alloc((size_t)2 * N_NODES * 4);
    int*   fillc     = counts + N_NODES;
    int*   row_start = (int*)alloc((size_t)(N_NODES + 1) * 4);
    int*   csr_eid   = (int*)alloc((size_t)N_EDGES * 4);
    int*   csr_src   = (int*)alloc((size_t)N_EDGES * 4);
    unsigned char*  e_fp8 = (unsigned char*)alloc((size_t)N_EDGES * DIM);
    unsigned short* h0b   = (unsigned short*)alloc((size_t)N_NODES * DIM * 2);
    unsigned short* h1b   = (unsigned short*)alloc((size_t)N_NODES * DIM * 2);
    unsigned short* h2b   = (unsigned short*)alloc((size_t)N_NODES * DIM * 2);
    unsigned short* h3b   = (unsigned short*)alloc((size_t)N_NODES * DIM * 2);
    unsigned short* attnb = (unsigned short*)alloc((size_t)N_NODES * DIM * 2);
    unsigned short* hidb  = (unsigned short*)alloc((size_t)N_NODES * FF_HIDDEN * 2);
    unsigned short* wxT   = (unsigned short*)alloc((size_t)DIM * DIM * 2);
    unsigned short* weT   = (unsigned short*)alloc((size_t)DIM * EDGE_DIM * 2);
    unsigned short* wff1T = (unsigned short*)alloc((size_t)FF_HIDDEN * DIM * 2);
    unsigned short* wff2T = (unsigned short*)alloc((size_t)DIM * FF_HIDDEN * 2);
    if (off > ws_size) return;

    const int egrid = (N_EDGES + 255) / 256;

    hipMemsetAsync(counts, 0, (size_t)2 * N_NODES * 4, stream);
    detect_kernel<<<1, 256, 0, stream>>>(ei, flag);
    convert_kernel<<<egrid, 256, 0, stream>>>(ei, flag, src32, dst32, counts);
    scan_kernel<<<1, 256, 0, stream>>>(counts, row_start);
    fill_kernel<<<egrid, 256, 0, stream>>>(src32, dst32, row_start, fillc, csr_eid, csr_src);

    wconv_kernel<<<(DIM * DIM + 255) / 256, 256, 0, stream>>>(W_x, wxT, DIM, DIM);
    wconv_kernel<<<(EDGE_DIM * DIM + 255) / 256, 256, 0, stream>>>(W_e, weT, EDGE_DIM, DIM);
    wconv_kernel<<<(DIM * FF_HIDDEN + 255) / 256, 256, 0, stream>>>(W_ff1, wff1T, DIM, FF_HIDDEN);
    wconv_kernel<<<(FF_HIDDEN * DIM + 255) / 256, 256, 0, stream>>>(W_ff2, wff2T, FF_HIDDEN, DIM);

    // h0 = x @ W_x -> bf16
    wgemm<false, 0><<<dim3(157, 1), 256, 0, stream>>>(x, wxT, h0b,
        N_NODES, DIM, DIM, nullptr, nullptr);
    // e = edge_attr(gathered) @ W_e -> fp8, sequential CSR-order stores
    egemm_fp8<<<N_EDGES / 64, 256, 0, stream>>>(edge_attr, weT, e_fp8, csr_eid);

    hop_kernel<<<N_NODES / 4, 256, 0, stream>>>(h0b, nullptr, e_fp8, row_start, csr_src, h1b);
    hop_kernel<<<N_NODES / 4, 256, 0, stream>>>(h1b, h0b,     e_fp8, row_start, csr_src, h2b);
    hop_kernel<<<N_NODES / 4, 256, 0, stream>>>(h2b, h1b,     e_fp8, row_start, csr_src, h3b);

    attn_kernel<<<N_NODES, 256, 0, stream>>>(h0b, h1b, h2b, h3b, att_a, attnb);

    // hidden = relu(attn @ W_ff1) -> bf16
    wgemm<true, 1><<<dim3(157, 2), 256, 0, stream>>>(attnb, wff1T, hidb,
        N_NODES, DIM, FF_HIDDEN, nullptr, nullptr);
    // d_out = x + relu(attn + hidden @ W_ff2)
    wgemm<true, 2><<<dim3(157, 1), 256, 0, stream>>>(hidb, wff2T, d_out,
        N_NODES, FF_HIDDEN, DIM, attnb, x);
}

// Round 13
// 343.667 us; speedup vs baseline: 1.7708x; 1.0066x over previous
//
#include <hip/hip_runtime.h>
#include <hip/hip_bf16.h>

#define N_NODES   10000
#define N_EDGES   320000
#define DIM       256
#define EDGE_DIM  64
#define FF_HIDDEN 512
#define GAMMA     0.5f

typedef __attribute__((ext_vector_type(8))) short bf16x8;
typedef __attribute__((ext_vector_type(4))) float f32x4;

static __device__ __forceinline__ unsigned short f2b(float f)
{
    union { __hip_bfloat16 b; unsigned short u; } c;
    c.b = __float2bfloat16(f);
    return c.u;
}
static __device__ __forceinline__ float b2f(unsigned short u)
{
    union { unsigned u32; float f; } c;
    c.u32 = ((unsigned)u) << 16;
    return c.f;
}

// f32 -> fp8 e4m3fn (round-half-up, denormals flushed, clamp to 448).
static __device__ __forceinline__ unsigned f2fp8(float f)
{
    union { float f; unsigned u; } c; c.f = f;
    const unsigned s = (c.u >> 24) & 0x80u;
    int v = (int)(((c.u & 0x7FFFFFFFu) + 0x00080000u) >> 20) - 960;
    v = (v < 8) ? 0 : ((v > 126) ? 126 : v);
    return s | (unsigned)v;
}
// fp8 e4m3fn -> f32 (denormals -> 0)
static __device__ __forceinline__ float fp8tof(unsigned u)
{
    unsigned v = ((u & 0x7Fu) << 4) + 0x3C00u;
    v = (u & 0x78u) ? v : 0u;
    v |= (u & 0x80u) << 8;
    union { unsigned u; float f; } c; c.u = v << 16;
    return c.f;
}

static __device__ __forceinline__ bf16x8 load_a_frag(const float* __restrict__ p)
{
    const float4 f0 = *(const float4*)p;
    const float4 f1 = *(const float4*)(p + 4);
    bf16x8 r;
    r[0] = (short)f2b(f0.x); r[1] = (short)f2b(f0.y);
    r[2] = (short)f2b(f0.z); r[3] = (short)f2b(f0.w);
    r[4] = (short)f2b(f1.x); r[5] = (short)f2b(f1.y);
    r[6] = (short)f2b(f1.z); r[7] = (short)f2b(f1.w);
    return r;
}

// ---------------------------------------------------------------------------
__global__ __launch_bounds__(256) void detect_kernel(const unsigned* __restrict__ ei,
                                                     int* __restrict__ flag)
{
    __shared__ int bad;
    if (threadIdx.x == 0) bad = 0;
    __syncthreads();
    int b = 0;
    for (int i = threadIdx.x; i < 1024; i += 256)
        if (ei[2 * i + 1] != 0u) b = 1;
    if (b) atomicAdd(&bad, 1);
    __syncthreads();
    if (threadIdx.x == 0) *flag = (bad == 0) ? 1 : 0;
}

__global__ __launch_bounds__(256) void convert_kernel(const unsigned* __restrict__ ei,
                                                      const int* __restrict__ flag,
                                                      int* __restrict__ src, int* __restrict__ dst,
                                                      int* __restrict__ counts)
{
    const int i = blockIdx.x * 256 + threadIdx.x;
    if (i >= N_EDGES) return;
    const int f = *flag;
    int s, d;
    if (f) { s = (int)ei[2 * i]; d = (int)ei[2 * (N_EDGES + i)]; }
    else   { s = (int)ei[i];     d = (int)ei[N_EDGES + i]; }
    src[i] = s;
    dst[i] = d;
    atomicAdd(&counts[d], 1);
}

__global__ __launch_bounds__(256) void scan_kernel(const int* __restrict__ counts,
                                                   int* __restrict__ row_start)
{
    __shared__ int lds[256];
    const int t = threadIdx.x;
    int vals[40];
    int tot = 0;
    const int base = t * 40;
#pragma unroll
    for (int j = 0; j < 40; ++j) {
        const int idx = base + j;
        const int c = (idx < N_NODES) ? counts[idx] : 0;
        vals[j] = tot;
        tot += c;
    }
    lds[t] = tot;
    __syncthreads();
    for (int off = 1; off < 256; off <<= 1) {
        const int tmp = (t >= off) ? lds[t - off] : 0;
        __syncthreads();
        lds[t] += tmp;
        __syncthreads();
    }
    const int ebase = lds[t] - tot;
#pragma unroll
    for (int j = 0; j < 40; ++j) {
        const int idx = base + j;
        if (idx < N_NODES) row_start[idx] = ebase + vals[j];
    }
    if (t == 0) row_start[N_NODES] = N_EDGES;
}

// perm[edge] = CSR slot (for egemm scatter stores); csr_src[slot] = src node.
__global__ __launch_bounds__(256) void fill_kernel(const int* __restrict__ src,
                                                   const int* __restrict__ dst,
                                                   const int* __restrict__ row_start,
                                                   int* __restrict__ fillc,
                                                   int* __restrict__ perm,
                                                   int* __restrict__ csr_src)
{
    const int i = blockIdx.x * 256 + threadIdx.x;
    if (i >= N_EDGES) return;
    const int d = dst[i];
    const int pos = atomicAdd(&fillc[d], 1);
    const int slot = row_start[d] + pos;
    perm[i] = slot;
    csr_src[slot] = src[i];
}

// ---------------------------------------------------------------------------
__global__ __launch_bounds__(256) void wconv_kernel(const float* __restrict__ W,
                                                    unsigned short* __restrict__ wT,
                                                    int K, int N)
{
    const int i = blockIdx.x * 256 + threadIdx.x;
    if (i >= K * N) return;
    const int k = i / N, n = i - k * N;
    wT[(size_t)n * K + k] = f2b(W[i]);
}

// ---------------------------------------------------------------------------
// Wave-level register GEMM (no LDS), 4 waves/block, wave = 64x64 tile.
template <bool ABF16, int MODE>
__global__ __launch_bounds__(256) void wgemm(const void* __restrict__ Av,
                                             const unsigned short* __restrict__ wT,
                                             void* __restrict__ outv,
                                             int M, int K, int N,
                                             const unsigned short* __restrict__ epi_a,
                                             const float* __restrict__ epi_x)
{
    const int tid  = threadIdx.x;
    const int wave = tid >> 6;
    const int lane = tid & 63;
    const int l15  = lane & 15;
    const int l4   = lane >> 4;
    const int m0   = blockIdx.x * 64;
    const int n0   = blockIdx.y * 256 + wave * 64;

    f32x4 acc[4][4];
#pragma unroll
    for (int i = 0; i < 4; ++i)
#pragma unroll
        for (int j = 0; j < 4; ++j) acc[i][j] = f32x4{0.f, 0.f, 0.f, 0.f};

    int rowm[4];
#pragma unroll
    for (int i = 0; i < 4; ++i) rowm[i] = min(m0 + i * 16 + l15, M - 1);

    const int nk = K >> 6;
    for (int kt = 0; kt < nk; ++kt) {
        const int kb = kt * 64 + l4 * 8;
        bf16x8 bfr[2][4], afr[2][4];
#pragma unroll
        for (int ks = 0; ks < 2; ++ks)
#pragma unroll
            for (int j = 0; j < 4; ++j)
                bfr[ks][j] = *(const bf16x8*)(wT + (size_t)(n0 + j * 16 + l15) * K + kb + ks * 32);
#pragma unroll
        for (int ks = 0; ks < 2; ++ks)
#pragma unroll
            for (int i = 0; i < 4; ++i) {
                if (ABF16)
                    afr[ks][i] = *(const bf16x8*)((const unsigned short*)Av + (size_t)rowm[i] * K + kb + ks * 32);
                else
                    afr[ks][i] = load_a_frag((const float*)Av + (size_t)rowm[i] * K + kb + ks * 32);
            }
#pragma unroll
        for (int ks = 0; ks < 2; ++ks)
#pragma unroll
            for (int i = 0; i < 4; ++i)
#pragma unroll
                for (int j = 0; j < 4; ++j)
                    acc[i][j] = __builtin_amdgcn_mfma_f32_16x16x32_bf16(bfr[ks][j], afr[ks][i], acc[i][j], 0, 0, 0);
    }

#pragma unroll
    for (int i = 0; i < 4; ++i) {
        const int m = m0 + i * 16 + l15;
        if (m < M) {
#pragma unroll
            for (int j = 0; j < 4; ++j) {
                const size_t oi = (size_t)m * N + n0 + j * 16 + l4 * 4;
                if (MODE == 2) {
                    const ushort4 ea = *(const ushort4*)(epi_a + oi);
                    const float4  ex = *(const float4*)(epi_x + oi);
                    float4 v;
                    v.x = fmaxf(acc[i][j][0] + b2f(ea.x), 0.f) + ex.x;
                    v.y = fmaxf(acc[i][j][1] + b2f(ea.y), 0.f) + ex.y;
                    v.z = fmaxf(acc[i][j][2] + b2f(ea.z), 0.f) + ex.z;
                    v.w = fmaxf(acc[i][j][3] + b2f(ea.w), 0.f) + ex.w;
                    *(float4*)((float*)outv + oi) = v;
                } else {
                    float a0 = acc[i][j][0], a1 = acc[i][j][1];
                    float a2 = acc[i][j][2], a3 = acc[i][j][3];
                    if (MODE == 1) {
                        a0 = fmaxf(a0, 0.f); a1 = fmaxf(a1, 0.f);
                        a2 = fmaxf(a2, 0.f); a3 = fmaxf(a3, 0.f);
                    }
                    ushort4 u;
                    u.x = f2b(a0); u.y = f2b(a1); u.z = f2b(a2); u.w = f2b(a3);
                    *(ushort4*)((unsigned short*)outv + oi) = u;
                }
            }
        }
    }
}

// ---------------------------------------------------------------------------
// e-GEMM -> fp8, scatter-store flavor: block owns 64 CONSECUTIVE EDGES
// (edge_attr reads fully sequential, no indirection); fp8-encode through
// 64x272B LDS; store phase scatters each 256B row (4 full 64B lines) to its
// CSR slot perm[edge]. Stores have no consumer -> latency hidden.
__global__ __launch_bounds__(256) void egemm_fp8(const float* __restrict__ A,
                                                 const unsigned short* __restrict__ wT,
                                                 unsigned char* __restrict__ e_out,
                                                 const int* __restrict__ perm)
{
    __shared__ unsigned char et[64 * 272];   // 17408 B
    const int tid  = threadIdx.x;
    const int wave = tid >> 6;
    const int lane = tid & 63;
    const int l15  = lane & 15;
    const int l4   = lane >> 4;
    const int wc0  = wave * 64;
    const int m0   = blockIdx.x * 64;   // edge base (sequential)

    bf16x8 bfr[2][4];
#pragma unroll
    for (int ks = 0; ks < 2; ++ks)
#pragma unroll
        for (int j = 0; j < 4; ++j)
            bfr[ks][j] = *(const bf16x8*)(wT + (size_t)(wc0 + j * 16 + l15) * 64 + ks * 32 + l4 * 8);

    bf16x8 afr[2][4];
#pragma unroll
    for (int ks = 0; ks < 2; ++ks)
#pragma unroll
        for (int i = 0; i < 4; ++i)
            afr[ks][i] = load_a_frag(A + (size_t)(m0 + i * 16 + l15) * 64 + ks * 32 + l4 * 8);

    f32x4 acc[4][4];
#pragma unroll
    for (int i = 0; i < 4; ++i)
#pragma unroll
        for (int j = 0; j < 4; ++j) acc[i][j] = f32x4{0.f, 0.f, 0.f, 0.f};
#pragma unroll
    for (int ks = 0; ks < 2; ++ks)
#pragma unroll
        for (int i = 0; i < 4; ++i)
#pragma unroll
            for (int j = 0; j < 4; ++j)
                acc[i][j] = __builtin_amdgcn_mfma_f32_16x16x32_bf16(bfr[ks][j], afr[ks][i], acc[i][j], 0, 0, 0);

    // fp8-encode into LDS tile (4B per acc group)
#pragma unroll
    for (int i = 0; i < 4; ++i)
#pragma unroll
        for (int j = 0; j < 4; ++j) {
            const unsigned p = f2fp8(acc[i][j][0])
                             | (f2fp8(acc[i][j][1]) << 8)
                             | (f2fp8(acc[i][j][2]) << 16)
                             | (f2fp8(acc[i][j][3]) << 24);
            *(unsigned*)(&et[(i * 16 + l15) * 272 + wc0 + j * 16 + l4 * 4]) = p;
        }
    __syncthreads();

    // store: thread t -> local row t>>2 (scattered to perm), 64B chunk t&3
    const int row  = tid >> 2;
    const int orow = perm[m0 + row];
    const unsigned char* sp = et + row * 272 + (tid & 3) * 64;
    unsigned char* dp = e_out + (size_t)orow * 256 + (tid & 3) * 64;
#pragma unroll
    for (int v = 0; v < 4; ++v)
        *(uint4*)(dp + v * 16) = *(const uint4*)(sp + v * 16);
}

// ---------------------------------------------------------------------------
// Hop (r8 structure): wave-per-node, 4 dims/lane, 8-edge MLP unroll.
// e is fp8 in CSR order (pure sequential 256B rows); h bf16.
__global__ __launch_bounds__(256) void hop_kernel(const unsigned short* __restrict__ h_prev1,
                                                  const unsigned short* __restrict__ h_prev2,
                                                  const unsigned char* __restrict__ e,
                                                  const int* __restrict__ row_start,
                                                  const int* __restrict__ csr_src,
                                                  unsigned short* __restrict__ h_out)
{
    const int wave = threadIdx.x >> 6;
    const int lane = threadIdx.x & 63;
    const int n = blockIdx.x * 4 + wave;
    const int d4 = lane * 4;
    const int rb = row_start[n];
    const int re = row_start[n + 1];

    float4 acc = {0.f, 0.f, 0.f, 0.f};
    int s = rb;
    for (; s + 8 <= re; s += 8) {
        int idx[8];
        unsigned ev[8];
        ushort4 hv[8];
#pragma unroll
        for (int u = 0; u < 8; ++u) idx[u] = csr_src[s + u];
#pragma unroll
        for (int u = 0; u < 8; ++u) ev[u] = *(const unsigned*)(e + (size_t)(s + u) * 256 + d4);
#pragma unroll
        for (int u = 0; u < 8; ++u) hv[u] = *(const ushort4*)(h_prev1 + (size_t)idx[u] * DIM + d4);
#pragma unroll
        for (int u = 0; u < 8; ++u) {
            acc.x += fmaxf(b2f(hv[u].x) + fp8tof(ev[u] & 255u), 0.f);
            acc.y += fmaxf(b2f(hv[u].y) + fp8tof((ev[u] >> 8) & 255u), 0.f);
            acc.z += fmaxf(b2f(hv[u].z) + fp8tof((ev[u] >> 16) & 255u), 0.f);
            acc.w += fmaxf(b2f(hv[u].w) + fp8tof(ev[u] >> 24), 0.f);
        }
    }
    for (; s < re; ++s) {
        const int sr = csr_src[s];
        const unsigned ev = *(const unsigned*)(e + (size_t)s * 256 + d4);
        const ushort4 hv = *(const ushort4*)(h_prev1 + (size_t)sr * DIM + d4);
        acc.x += fmaxf(b2f(hv.x) + fp8tof(ev & 255u), 0.f);
        acc.y += fmaxf(b2f(hv.y) + fp8tof((ev >> 8) & 255u), 0.f);
        acc.z += fmaxf(b2f(hv.z) + fp8tof((ev >> 16) & 255u), 0.f);
        acc.w += fmaxf(b2f(hv.w) + fp8tof(ev >> 24), 0.f);
    }
    if (h_prev2) {
        const float gd = GAMMA * (float)(re - rb);
        const ushort4 p2 = *(const ushort4*)(h_prev2 + (size_t)n * DIM + d4);
        acc.x -= gd * b2f(p2.x); acc.y -= gd * b2f(p2.y);
        acc.z -= gd * b2f(p2.z); acc.w -= gd * b2f(p2.w);
    }
    ushort4 o;
    o.x = f2b(acc.x); o.y = f2b(acc.y); o.z = f2b(acc.z); o.w = f2b(acc.w);
    *(ushort4*)(h_out + (size_t)n * DIM + d4) = o;
}

// ---------------------------------------------------------------------------
__global__ __launch_bounds__(256) void attn_kernel(const unsigned short* __restrict__ h0,
                                                   const unsigned short* __restrict__ h1,
                                                   const unsigned short* __restrict__ h2,
                                                   const unsigned short* __restrict__ h3,
                                                   const float* __restrict__ att_a,
                                                   unsigned short* __restrict__ out)
{
    const int n = blockIdx.x;
    const int t = threadIdx.x;
    const size_t i = (size_t)n * DIM + t;
    const float q = b2f(h0[i]);
    float hk[4];
    hk[0] = q; hk[1] = b2f(h1[i]); hk[2] = b2f(h2[i]); hk[3] = b2f(h3[i]);
    const float a = att_a[t];
    float sc[4];
#pragma unroll
    for (int k = 0; k < 4; ++k) {
        float v = tanhf(hk[k] + q) * a;
#pragma unroll
        for (int off = 32; off > 0; off >>= 1)
            v += __shfl_xor(v, off, 64);
        sc[k] = v;
    }
    const float mx = fmaxf(fmaxf(sc[0], sc[1]), fmaxf(sc[2], sc[3]));
    float ex[4], se = 0.f;
#pragma unroll
    for (int k = 0; k < 4; ++k) { ex[k] = __expf(sc[k] - mx); se += ex[k]; }
    const float inv = 1.f / se;
    float o = 0.f;
#pragma unroll
    for (int k = 0; k < 4; ++k) o += ex[k] * inv * hk[k];
    out[i] = f2b(o);
}

// ---------------------------------------------------------------------------
extern "C" void kernel_launch(void* const* d_in, const int* in_sizes, int n_in,
                              void* d_out, int out_size, void* d_ws, size_t ws_size,
                              hipStream_t stream)
{
    const float*    x         = (const float*)d_in[0];
    const unsigned* ei        = (const unsigned*)d_in[1];
    const float*    edge_attr = (const float*)d_in[2];
    const float*    W_x       = (const float*)d_in[3];
    const float*    W_e       = (const float*)d_in[4];
    const float*    att_a     = (const float*)d_in[5];
    const float*    W_ff1     = (const float*)d_in[6];
    const float*    W_ff2     = (const float*)d_in[7];

    char* ws = (char*)d_ws;
    size_t off = 0;
    auto alloc = [&](size_t bytes) -> void* {
        void* p = ws + off;
        off = (off + bytes + 255) & ~(size_t)255;
        return p;
    };
    int*   flag      = (int*)alloc(4);
    int*   src32     = (int*)alloc((size_t)N_EDGES * 4);
    int*   dst32     = (int*)alloc((size_t)N_EDGES * 4);
    int*   counts    = (int*)alloc((size_t)2 * N_NODES * 4);
    int*   fillc     = counts + N_NODES;
    int*   row_start = (int*)alloc((size_t)(N_NODES + 1) * 4);
    int*   perm      = (int*)alloc((size_t)N_EDGES * 4);
    int*   csr_src   = (int*)alloc((size_t)N_EDGES * 4);
    unsigned char*  e_fp8 = (unsigned char*)alloc((size_t)N_EDGES * DIM);
    unsigned short* h0b   = (unsigned short*)alloc((size_t)N_NODES * DIM * 2);
    unsigned short* h1b   = (unsigned short*)alloc((size_t)N_NODES * DIM * 2);
    unsigned short* h2b   = (unsigned short*)alloc((size_t)N_NODES * DIM * 2);
    unsigned short* h3b   = (unsigned short*)alloc((size_t)N_NODES * DIM * 2);
    unsigned short* attnb = (unsigned short*)alloc((size_t)N_NODES * DIM * 2);
    unsigned short* hidb  = (unsigned short*)alloc((size_t)N_NODES * FF_HIDDEN * 2);
    unsigned short* wxT   = (unsigned short*)alloc((size_t)DIM * DIM * 2);
    unsigned short* weT   = (unsigned short*)alloc((size_t)DIM * EDGE_DIM * 2);
    unsigned short* wff1T = (unsigned short*)alloc((size_t)FF_HIDDEN * DIM * 2);
    unsigned short* wff2T = (unsigned short*)alloc((size_t)DIM * FF_HIDDEN * 2);
    if (off > ws_size) return;

    const int egrid = (N_EDGES + 255) / 256;

    hipMemsetAsync(counts, 0, (size_t)2 * N_NODES * 4, stream);
    detect_kernel<<<1, 256, 0, stream>>>(ei, flag);
    convert_kernel<<<egrid, 256, 0, stream>>>(ei, flag, src32, dst32, counts);
    scan_kernel<<<1, 256, 0, stream>>>(counts, row_start);
    fill_kernel<<<egrid, 256, 0, stream>>>(src32, dst32, row_start, fillc, perm, csr_src);

    wconv_kernel<<<(DIM * DIM + 255) / 256, 256, 0, stream>>>(W_x, wxT, DIM, DIM);
    wconv_kernel<<<(EDGE_DIM * DIM + 255) / 256, 256, 0, stream>>>(W_e, weT, EDGE_DIM, DIM);
    wconv_kernel<<<(DIM * FF_HIDDEN + 255) / 256, 256, 0, stream>>>(W_ff1, wff1T, DIM, FF_HIDDEN);
    wconv_kernel<<<(FF_HIDDEN * DIM + 255) / 256, 256, 0, stream>>>(W_ff2, wff2T, FF_HIDDEN, DIM);

    // h0 = x @ W_x -> bf16
    wgemm<false, 0><<<dim3(157, 1), 256, 0, stream>>>(x, wxT, h0b,
        N_NODES, DIM, DIM, nullptr, nullptr);
    // e = edge_attr @ W_e -> fp8, sequential reads, full-line scatter stores
    egemm_fp8<<<N_EDGES / 64, 256, 0, stream>>>(edge_attr, weT, e_fp8, perm);

    hop_kernel<<<N_NODES / 4, 256, 0, stream>>>(h0b, nullptr, e_fp8, row_start, csr_src, h1b);
    hop_kernel<<<N_NODES / 4, 256, 0, stream>>>(h1b, h0b,     e_fp8, row_start, csr_src, h2b);
    hop_kernel<<<N_NODES / 4, 256, 0, stream>>>(h2b, h1b,     e_fp8, row_start, csr_src, h3b);

    attn_kernel<<<N_NODES, 256, 0, stream>>>(h0b, h1b, h2b, h3b, att_a, attnb);

    // hidden = relu(attn @ W_ff1) -> bf16
    wgemm<true, 1><<<dim3(157, 2), 256, 0, stream>>>(attnb, wff1T, hidb,
        N_NODES, DIM, FF_HIDDEN, nullptr, nullptr);
    // d_out = x + relu(attn + hidden @ W_ff2)
    wgemm<true, 2><<<dim3(157, 1), 256, 0, stream>>>(hidb, wff2T, d_out,
        N_NODES, FF_HIDDEN, DIM, attnb, x);
}